// Round 1
// baseline (3397.094 us; speedup 1.0000x reference)
//
#include <hip/hip_runtime.h>
#include <hip/hip_bf16.h>

// GIN 2-layer forward on MI355X.
// Stages:
//   agg1 = segment_sum(x[src], dst)            (atomicAdd scatter)
//   t1   = relu((x+agg1)@w1 + b1)              (fused-add GEMM)
//   h1   = relu(t1@w2 + b2)                    (conv1 out + inter-layer relu fused)
//   agg2 = segment_sum(h1[src], dst)
//   t2   = relu((h1+agg2)@w3 + b3)
//   out  = log_softmax(t2@w4 + b4)             (per-wave head)

// ---------------- scatter-add (segment_sum) ----------------
__global__ __launch_bounds__(256) void scatter_add_kernel(
    const float* __restrict__ feat,
    const int* __restrict__ src,
    const int* __restrict__ dst,
    float* __restrict__ agg,
    int E, int dv_shift, int D)
{
    const int gid = blockIdx.x * 256 + threadIdx.x;
    const int Dv = 1 << dv_shift;          // D/4 float4 chunks per edge
    if (gid >= E * Dv) return;
    const int e = gid >> dv_shift;
    const int c = (gid & (Dv - 1)) << 2;
    const int s = src[e];
    const int d = dst[e];
    const float4 v = *(const float4*)(feat + (size_t)s * D + c);
    float* p = agg + (size_t)d * D + c;
    atomicAdd(p + 0, v.x);
    atomicAdd(p + 1, v.y);
    atomicAdd(p + 2, v.z);
    atomicAdd(p + 3, v.w);
}

// ---------------- fused GEMM: C = act((A1[+A2])@B + bias) ----------------
// A: M x K row-major, B: K x N row-major, C: M x N row-major.
// Tile 64x64xBK32, 256 threads, 4x4 per thread. K % 32 == 0, N % 64 == 0.
__global__ __launch_bounds__(256) void gemm_bias_act(
    const float* __restrict__ A1, const float* __restrict__ A2,
    const float* __restrict__ B, const float* __restrict__ bias,
    float* __restrict__ C,
    int M, int K, int N, int do_relu)
{
    __shared__ float As[64][33];   // [m][k], +1 pad breaks 4-way bank conflict on a-reads
    __shared__ float Bs[32][64];   // [k][n], float4 reads along n are conflict-free

    const int tid = threadIdx.x;
    const int tx = tid & 15;       // n-tile position
    const int ty = tid >> 4;       // m-tile position
    const int bm = blockIdx.x;
    const int bn = blockIdx.y;

    float acc[4][4] = {};

    for (int k0 = 0; k0 < K; k0 += 32) {
        // stage A tile (64 rows x 32 k), coalesced float4, optional A2 addend
        {
            const int c4 = (tid & 7) * 4;
            #pragma unroll
            for (int rr = tid >> 3; rr < 64; rr += 32) {
                const int gm = bm * 64 + rr;
                float4 v = make_float4(0.f, 0.f, 0.f, 0.f);
                if (gm < M) {
                    const size_t off = (size_t)gm * K + k0 + c4;
                    v = *(const float4*)(A1 + off);
                    if (A2) {
                        const float4 w = *(const float4*)(A2 + off);
                        v.x += w.x; v.y += w.y; v.z += w.z; v.w += w.w;
                    }
                }
                As[rr][c4 + 0] = v.x;
                As[rr][c4 + 1] = v.y;
                As[rr][c4 + 2] = v.z;
                As[rr][c4 + 3] = v.w;
            }
        }
        // stage B tile (32 k x 64 n), coalesced float4
        {
            const int c4 = (tid & 15) * 4;
            #pragma unroll
            for (int kr = tid >> 4; kr < 32; kr += 16) {
                const float4 v = *(const float4*)(B + (size_t)(k0 + kr) * N + bn * 64 + c4);
                *(float4*)&Bs[kr][c4] = v;
            }
        }
        __syncthreads();

        #pragma unroll
        for (int kk = 0; kk < 32; ++kk) {
            const float4 bv = *(const float4*)&Bs[kk][tx * 4];
            const float a0 = As[ty * 4 + 0][kk];
            const float a1 = As[ty * 4 + 1][kk];
            const float a2 = As[ty * 4 + 2][kk];
            const float a3 = As[ty * 4 + 3][kk];
            acc[0][0] += a0 * bv.x; acc[0][1] += a0 * bv.y; acc[0][2] += a0 * bv.z; acc[0][3] += a0 * bv.w;
            acc[1][0] += a1 * bv.x; acc[1][1] += a1 * bv.y; acc[1][2] += a1 * bv.z; acc[1][3] += a1 * bv.w;
            acc[2][0] += a2 * bv.x; acc[2][1] += a2 * bv.y; acc[2][2] += a2 * bv.z; acc[2][3] += a2 * bv.w;
            acc[3][0] += a3 * bv.x; acc[3][1] += a3 * bv.y; acc[3][2] += a3 * bv.z; acc[3][3] += a3 * bv.w;
        }
        __syncthreads();
    }

    // epilogue: bias + optional relu, float4 stores
    const int row0 = bm * 64 + ty * 4;
    const int col0 = bn * 64 + tx * 4;
    const float4 bv = *(const float4*)(bias + col0);
    #pragma unroll
    for (int i = 0; i < 4; ++i) {
        const int r = row0 + i;
        if (r >= M) break;
        float4 v;
        v.x = acc[i][0] + bv.x;
        v.y = acc[i][1] + bv.y;
        v.z = acc[i][2] + bv.z;
        v.w = acc[i][3] + bv.w;
        if (do_relu) {
            v.x = fmaxf(v.x, 0.f); v.y = fmaxf(v.y, 0.f);
            v.z = fmaxf(v.z, 0.f); v.w = fmaxf(v.w, 0.f);
        }
        *(float4*)(C + (size_t)r * N + col0) = v;
    }
}

// ---------------- head: out = log_softmax(t2 @ w4 + b4), d_out = 2 ----------------
// one wave (64 lanes) per row; K = 256 -> 4 elements/lane; shuffle reduce.
__global__ __launch_bounds__(256) void head_logsoftmax_kernel(
    const float* __restrict__ t2, const float* __restrict__ w4,
    const float* __restrict__ b4, float* __restrict__ out, int M)
{
    const int g = blockIdx.x * 256 + threadIdx.x;
    const int row = g >> 6;
    const int lane = g & 63;
    if (row >= M) return;
    const float* a = t2 + (size_t)row * 256;
    float s0 = 0.f, s1 = 0.f;
    #pragma unroll
    for (int i = 0; i < 4; ++i) {
        const int k = lane + i * 64;
        const float av = a[k];
        const float2 w = *(const float2*)(w4 + 2 * k);   // w4 is (256,2) row-major
        s0 += av * w.x;
        s1 += av * w.y;
    }
    #pragma unroll
    for (int off = 32; off > 0; off >>= 1) {
        s0 += __shfl_down(s0, off);
        s1 += __shfl_down(s1, off);
    }
    if (lane == 0) {
        s0 += b4[0];
        s1 += b4[1];
        const float m = fmaxf(s0, s1);
        const float l = logf(__expf(s0 - m) + __expf(s1 - m));
        out[(size_t)row * 2 + 0] = s0 - m - l;
        out[(size_t)row * 2 + 1] = s1 - m - l;
    }
}

extern "C" void kernel_launch(void* const* d_in, const int* in_sizes, int n_in,
                              void* d_out, int out_size, void* d_ws, size_t ws_size,
                              hipStream_t stream)
{
    const float* x  = (const float*)d_in[0];
    const int*   ei = (const int*)d_in[1];
    const float* w1 = (const float*)d_in[2];
    const float* b1 = (const float*)d_in[3];
    const float* w2 = (const float*)d_in[4];
    const float* b2 = (const float*)d_in[5];
    const float* w3 = (const float*)d_in[6];
    const float* b3 = (const float*)d_in[7];
    const float* w4 = (const float*)d_in[8];
    const float* b4 = (const float*)d_in[9];

    const int DIN = 128, DH = 256;
    const int M = in_sizes[0] / DIN;   // 50000 nodes
    const int E = in_sizes[1] / 2;     // 600000 edges
    const int* src = ei;
    const int* dst = ei + E;

    // workspace layout (floats): agg | t1 (reused as t2) | h1  -> ~153.6 MB
    float* agg = (float*)d_ws;                    // M * 256
    float* t1  = agg + (size_t)M * DH;            // M * 256
    float* h1  = t1  + (size_t)M * DH;            // M * 256
    float* t2  = t1;                              // t1 dead after GEMM2

    dim3 gemm_grid((M + 63) / 64, DH / 64);

    // ---- layer 1 ----
    hipMemsetAsync(agg, 0, (size_t)M * DIN * sizeof(float), stream);
    {
        const int total = E * (DIN / 4);
        scatter_add_kernel<<<(total + 255) / 256, 256, 0, stream>>>(x, src, dst, agg, E, 5, DIN);
    }
    gemm_bias_act<<<gemm_grid, 256, 0, stream>>>(x,  agg,     w1, b1, t1, M, DIN, DH, 1);
    gemm_bias_act<<<gemm_grid, 256, 0, stream>>>(t1, nullptr, w2, b2, h1, M, DH,  DH, 1);

    // ---- layer 2 ----
    hipMemsetAsync(agg, 0, (size_t)M * DH * sizeof(float), stream);
    {
        const int total = E * (DH / 4);
        scatter_add_kernel<<<(total + 255) / 256, 256, 0, stream>>>(h1, src, dst, agg, E, 6, DH);
    }
    gemm_bias_act<<<gemm_grid, 256, 0, stream>>>(h1, agg, w3, b3, t2, M, DH, DH, 1);

    // ---- head ----
    head_logsoftmax_kernel<<<(M * 64 + 255) / 256, 256, 0, stream>>>(t2, w4, b4, (float*)d_out, M);
}

// Round 2
// 670.773 us; speedup vs baseline: 5.0644x; 5.0644x over previous
//
#include <hip/hip_runtime.h>
#include <hip/hip_bf16.h>

// GIN 2-layer forward on MI355X — R2: atomic-free aggregation via CSR gather.
//
// Stages (all on `stream`):
//   deg/scan/fill      build CSR over dst (rebuilt every call — ws is poisoned)
//   h1in = x  + gather(x)        (wave-per-row, float2 lanes, D=128)
//   t1   = relu(h1in@w1 + b1)
//   h1   = relu(t1@w2 + b2)      (conv1 out + inter-layer relu fused)
//   h2in = h1 + gather(h1)       (wave-per-row, float4 lanes, D=256)
//   t2   = relu(h2in@w3 + b3)
//   out  = log_softmax(t2@w4 + b4)

// ---------------- CSR build ----------------
__global__ __launch_bounds__(256) void degree_kernel(
    const int* __restrict__ dst, int* __restrict__ deg, int E)
{
    const int e = blockIdx.x * 256 + threadIdx.x;
    if (e < E) atomicAdd(&deg[dst[e]], 1);
}

#define SCAN_THREADS 1024
__global__ __launch_bounds__(SCAN_THREADS) void scan_kernel(
    const int* __restrict__ deg, int* __restrict__ rowptr, int* __restrict__ cur, int M)
{
    __shared__ int part[SCAN_THREADS];
    const int t = threadIdx.x;
    const int chunk = (M + SCAN_THREADS - 1) / SCAN_THREADS;
    const int lo = min(t * chunk, M);
    const int hi = min(lo + chunk, M);
    int s = 0;
    for (int i = lo; i < hi; ++i) s += deg[i];
    part[t] = s;
    __syncthreads();
    // Hillis-Steele inclusive scan over 1024 partials
    for (int off = 1; off < SCAN_THREADS; off <<= 1) {
        int v = (t >= off) ? part[t - off] : 0;
        __syncthreads();
        part[t] += v;
        __syncthreads();
    }
    int run = (t == 0) ? 0 : part[t - 1];   // exclusive prefix of my chunk
    for (int i = lo; i < hi; ++i) {
        rowptr[i] = run;
        cur[i] = run;
        run += deg[i];
    }
    if (t == SCAN_THREADS - 1) rowptr[M] = run;   // == E (tail threads inherit full sum)
}

__global__ __launch_bounds__(256) void fill_kernel(
    const int* __restrict__ src, const int* __restrict__ dst,
    int* __restrict__ cur, int* __restrict__ srcs, int E)
{
    const int e = blockIdx.x * 256 + threadIdx.x;
    if (e >= E) return;
    const int p = atomicAdd(&cur[dst[e]], 1);
    srcs[p] = src[e];
}

// ---------------- gather-aggregate (h = x + sum_{j->i} x[j]) ----------------
// One wave per destination row; neighbor row loads are 512B/1KB coalesced.
__global__ __launch_bounds__(256) void gather_add_d128(
    const float* __restrict__ feat, const int* __restrict__ rowptr,
    const int* __restrict__ srcs, float* __restrict__ outbuf, int M)
{
    const int row = blockIdx.x * 4 + (threadIdx.x >> 6);
    if (row >= M) return;
    const int o = (threadIdx.x & 63) * 2;
    float2 acc = *(const float2*)(feat + (size_t)row * 128 + o);   // self term (eps=0)
    const int jb = rowptr[row], je = rowptr[row + 1];
    int s_next = (jb < je) ? srcs[jb] : 0;
    for (int j = jb; j < je; ++j) {
        const int s = s_next;
        if (j + 1 < je) s_next = srcs[j + 1];          // prefetch index ahead of row load
        const float2 v = *(const float2*)(feat + (size_t)s * 128 + o);
        acc.x += v.x; acc.y += v.y;
    }
    *(float2*)(outbuf + (size_t)row * 128 + o) = acc;
}

__global__ __launch_bounds__(256) void gather_add_d256(
    const float* __restrict__ feat, const int* __restrict__ rowptr,
    const int* __restrict__ srcs, float* __restrict__ outbuf, int M)
{
    const int row = blockIdx.x * 4 + (threadIdx.x >> 6);
    if (row >= M) return;
    const int o = (threadIdx.x & 63) * 4;
    float4 acc = *(const float4*)(feat + (size_t)row * 256 + o);   // self term
    const int jb = rowptr[row], je = rowptr[row + 1];
    int s_next = (jb < je) ? srcs[jb] : 0;
    for (int j = jb; j < je; ++j) {
        const int s = s_next;
        if (j + 1 < je) s_next = srcs[j + 1];
        const float4 v = *(const float4*)(feat + (size_t)s * 256 + o);
        acc.x += v.x; acc.y += v.y; acc.z += v.z; acc.w += v.w;
    }
    *(float4*)(outbuf + (size_t)row * 256 + o) = acc;
}

// ---------------- GEMM: C = act(A@B + bias) ----------------
// A: M x K row-major, B: K x N row-major, C: M x N row-major.
// Tile 64x64xBK32, 256 threads, 4x4 per thread. K % 32 == 0, N % 64 == 0.
__global__ __launch_bounds__(256) void gemm_bias_act(
    const float* __restrict__ A1,
    const float* __restrict__ B, const float* __restrict__ bias,
    float* __restrict__ C,
    int M, int K, int N, int do_relu)
{
    __shared__ float As[64][33];   // [m][k], +1 pad breaks bank conflict on a-reads
    __shared__ float Bs[32][64];   // [k][n], float4 reads along n are conflict-free

    const int tid = threadIdx.x;
    const int tx = tid & 15;       // n-tile position
    const int ty = tid >> 4;       // m-tile position
    const int bm = blockIdx.x;
    const int bn = blockIdx.y;

    float acc[4][4] = {};

    for (int k0 = 0; k0 < K; k0 += 32) {
        {
            const int c4 = (tid & 7) * 4;
            #pragma unroll
            for (int rr = tid >> 3; rr < 64; rr += 32) {
                const int gm = bm * 64 + rr;
                float4 v = make_float4(0.f, 0.f, 0.f, 0.f);
                if (gm < M) v = *(const float4*)(A1 + (size_t)gm * K + k0 + c4);
                As[rr][c4 + 0] = v.x;
                As[rr][c4 + 1] = v.y;
                As[rr][c4 + 2] = v.z;
                As[rr][c4 + 3] = v.w;
            }
        }
        {
            const int c4 = (tid & 15) * 4;
            #pragma unroll
            for (int kr = tid >> 4; kr < 32; kr += 16) {
                const float4 v = *(const float4*)(B + (size_t)(k0 + kr) * N + bn * 64 + c4);
                *(float4*)&Bs[kr][c4] = v;
            }
        }
        __syncthreads();

        #pragma unroll
        for (int kk = 0; kk < 32; ++kk) {
            const float4 bv = *(const float4*)&Bs[kk][tx * 4];
            const float a0 = As[ty * 4 + 0][kk];
            const float a1 = As[ty * 4 + 1][kk];
            const float a2 = As[ty * 4 + 2][kk];
            const float a3 = As[ty * 4 + 3][kk];
            acc[0][0] += a0 * bv.x; acc[0][1] += a0 * bv.y; acc[0][2] += a0 * bv.z; acc[0][3] += a0 * bv.w;
            acc[1][0] += a1 * bv.x; acc[1][1] += a1 * bv.y; acc[1][2] += a1 * bv.z; acc[1][3] += a1 * bv.w;
            acc[2][0] += a2 * bv.x; acc[2][1] += a2 * bv.y; acc[2][2] += a2 * bv.z; acc[2][3] += a2 * bv.w;
            acc[3][0] += a3 * bv.x; acc[3][1] += a3 * bv.y; acc[3][2] += a3 * bv.z; acc[3][3] += a3 * bv.w;
        }
        __syncthreads();
    }

    const int row0 = bm * 64 + ty * 4;
    const int col0 = bn * 64 + tx * 4;
    const float4 bv = *(const float4*)(bias + col0);
    #pragma unroll
    for (int i = 0; i < 4; ++i) {
        const int r = row0 + i;
        if (r >= M) break;
        float4 v;
        v.x = acc[i][0] + bv.x;
        v.y = acc[i][1] + bv.y;
        v.z = acc[i][2] + bv.z;
        v.w = acc[i][3] + bv.w;
        if (do_relu) {
            v.x = fmaxf(v.x, 0.f); v.y = fmaxf(v.y, 0.f);
            v.z = fmaxf(v.z, 0.f); v.w = fmaxf(v.w, 0.f);
        }
        *(float4*)(C + (size_t)r * N + col0) = v;
    }
}

// ---------------- head: out = log_softmax(t2 @ w4 + b4), d_out = 2 ----------------
__global__ __launch_bounds__(256) void head_logsoftmax_kernel(
    const float* __restrict__ t2, const float* __restrict__ w4,
    const float* __restrict__ b4, float* __restrict__ out, int M)
{
    const int g = blockIdx.x * 256 + threadIdx.x;
    const int row = g >> 6;
    const int lane = g & 63;
    if (row >= M) return;
    const float* a = t2 + (size_t)row * 256;
    float s0 = 0.f, s1 = 0.f;
    #pragma unroll
    for (int i = 0; i < 4; ++i) {
        const int k = lane + i * 64;
        const float av = a[k];
        const float2 w = *(const float2*)(w4 + 2 * k);   // w4 is (256,2) row-major
        s0 += av * w.x;
        s1 += av * w.y;
    }
    #pragma unroll
    for (int off = 32; off > 0; off >>= 1) {
        s0 += __shfl_down(s0, off);
        s1 += __shfl_down(s1, off);
    }
    if (lane == 0) {
        s0 += b4[0];
        s1 += b4[1];
        const float m = fmaxf(s0, s1);
        const float l = logf(__expf(s0 - m) + __expf(s1 - m));
        out[(size_t)row * 2 + 0] = s0 - m - l;
        out[(size_t)row * 2 + 1] = s1 - m - l;
    }
}

extern "C" void kernel_launch(void* const* d_in, const int* in_sizes, int n_in,
                              void* d_out, int out_size, void* d_ws, size_t ws_size,
                              hipStream_t stream)
{
    const float* x  = (const float*)d_in[0];
    const int*   ei = (const int*)d_in[1];
    const float* w1 = (const float*)d_in[2];
    const float* b1 = (const float*)d_in[3];
    const float* w2 = (const float*)d_in[4];
    const float* b2 = (const float*)d_in[5];
    const float* w3 = (const float*)d_in[6];
    const float* b3 = (const float*)d_in[7];
    const float* w4 = (const float*)d_in[8];
    const float* b4 = (const float*)d_in[9];

    const int DIN = 128, DH = 256;
    const int M = in_sizes[0] / DIN;   // 50000 nodes
    const int E = in_sizes[1] / 2;     // 600000 edges
    const int* src = ei;
    const int* dst = ei + E;

    // -------- workspace layout --------
    // ints:   deg[M] | cur[M] | rowptr[M+1] | srcs[E]
    // floats: h1in[M*128] | t1[M*256] | h1[M*256]
    //   h2in aliases t1 (t1 dead after GEMM2); t2 aliases h1 (h1 dead after gather2).
    int* deg    = (int*)d_ws;
    int* cur    = deg + M;
    int* rowptr = cur + M;
    int* srcs   = rowptr + (M + 1);
    size_t int_bytes = ((size_t)(3 * M + 1 + E) * sizeof(int) + 255) & ~(size_t)255;
    float* h1in = (float*)((char*)d_ws + int_bytes);        // M*128
    float* t1   = h1in + (size_t)M * DIN;                   // M*256
    float* h1   = t1   + (size_t)M * DH;                    // M*256
    float* h2in = t1;
    float* t2   = h1;

    // -------- CSR build (by dst) --------
    hipMemsetAsync(deg, 0, (size_t)M * sizeof(int), stream);
    degree_kernel<<<(E + 255) / 256, 256, 0, stream>>>(dst, deg, E);
    scan_kernel<<<1, SCAN_THREADS, 0, stream>>>(deg, rowptr, cur, M);
    fill_kernel<<<(E + 255) / 256, 256, 0, stream>>>(src, dst, cur, srcs, E);

    dim3 gemm_grid((M + 63) / 64, DH / 64);

    // -------- layer 1 --------
    gather_add_d128<<<(M + 3) / 4, 256, 0, stream>>>(x, rowptr, srcs, h1in, M);
    gemm_bias_act<<<gemm_grid, 256, 0, stream>>>(h1in, w1, b1, t1, M, DIN, DH, 1);
    gemm_bias_act<<<gemm_grid, 256, 0, stream>>>(t1,   w2, b2, h1, M, DH,  DH, 1);

    // -------- layer 2 --------
    gather_add_d256<<<(M + 3) / 4, 256, 0, stream>>>(h1, rowptr, srcs, h2in, M);
    gemm_bias_act<<<gemm_grid, 256, 0, stream>>>(h2in, w3, b3, t2, M, DH, DH, 1);

    // -------- head --------
    head_logsoftmax_kernel<<<(M * 64 + 255) / 256, 256, 0, stream>>>(t2, w4, b4, (float*)d_out, M);
}

// Round 3
// 413.940 us; speedup vs baseline: 8.2067x; 1.6205x over previous
//
#include <hip/hip_runtime.h>
#include <hip/hip_bf16.h>

// GIN 2-layer forward — R3: bf16 MFMA, fused layers, barrier-free K-loops.
//
//   CSR build (deg/scan/fill)
//   x_bf  = bf16(x);  w{1,2,3}t = bf16(w^T) padded
//   h1in  = x_bf + gather(x_bf)                     [bf16, stride 136]
//   h1    = relu(relu(h1in@w1+b1)@w2+b2)            [layer1_fused, t1 in LDS only]
//   h2in  = h1 + gather(h1)                         [bf16, stride 264]
//   out   = log_softmax(relu(h2in@w3+b3)@w4+b4)     [layer2_fused, t2 in LDS only]

typedef __attribute__((ext_vector_type(8))) short bf16x8;
typedef __attribute__((ext_vector_type(4))) float f32x4;

static __device__ __forceinline__ unsigned short f2bf(float f) {
    unsigned int u = __float_as_uint(f);
    unsigned int r = (u + 0x7fffu + ((u >> 16) & 1u)) >> 16;
    return (unsigned short)r;
}
static __device__ __forceinline__ float bf2f(unsigned short s) {
    return __uint_as_float(((unsigned int)s) << 16);
}

#define S1 136   // 128 + 8 pad (bf16 elems)
#define S2 264   // 256 + 8 pad

// ---------------- CSR build ----------------
__global__ __launch_bounds__(256) void degree_kernel(
    const int* __restrict__ dst, int* __restrict__ deg, int E)
{
    const int e = blockIdx.x * 256 + threadIdx.x;
    if (e < E) atomicAdd(&deg[dst[e]], 1);
}

#define SCAN_THREADS 1024
__global__ __launch_bounds__(SCAN_THREADS) void scan_kernel(
    const int* __restrict__ deg, int* __restrict__ rowptr, int* __restrict__ cur, int M)
{
    __shared__ int part[SCAN_THREADS];
    const int t = threadIdx.x;
    const int chunk = (M + SCAN_THREADS - 1) / SCAN_THREADS;
    const int lo = min(t * chunk, M);
    const int hi = min(lo + chunk, M);
    int s = 0;
    for (int i = lo; i < hi; ++i) s += deg[i];
    part[t] = s;
    __syncthreads();
    for (int off = 1; off < SCAN_THREADS; off <<= 1) {
        int v = (t >= off) ? part[t - off] : 0;
        __syncthreads();
        part[t] += v;
        __syncthreads();
    }
    int run = (t == 0) ? 0 : part[t - 1];
    for (int i = lo; i < hi; ++i) {
        rowptr[i] = run;
        cur[i] = run;
        run += deg[i];
    }
    if (t == SCAN_THREADS - 1) rowptr[M] = run;
}

__global__ __launch_bounds__(256) void fill_kernel(
    const int* __restrict__ src, const int* __restrict__ dst,
    int* __restrict__ cur, int* __restrict__ srcs, int E)
{
    const int e = blockIdx.x * 256 + threadIdx.x;
    if (e >= E) return;
    const int p = atomicAdd(&cur[dst[e]], 1);
    srcs[p] = src[e];
}

// ---------------- converts ----------------
__global__ __launch_bounds__(256) void cvt_bf16_kernel(
    const float* __restrict__ in, short* __restrict__ outb, int n4)
{
    const int i = (blockIdx.x * 256 + threadIdx.x);
    if (i >= n4) return;
    const float4 v = *(const float4*)(in + (size_t)i * 4);
    ushort4 o;
    o.x = f2bf(v.x); o.y = f2bf(v.y); o.z = f2bf(v.z); o.w = f2bf(v.w);
    *(ushort4*)(outb + (size_t)i * 4) = o;
}

// out[n][k] (bf16, row stride ostride) = in[k][n] (fp32, K x N)
__global__ __launch_bounds__(256) void transpose_cvt_kernel(
    const float* __restrict__ in, short* __restrict__ outb,
    int K, int N, int ostride)
{
    __shared__ float tile[32][33];
    const int k0 = blockIdx.x * 32;
    const int n0 = blockIdx.y * 32;
    const int tx = threadIdx.x & 31;
    const int ty = threadIdx.x >> 5;   // 0..7
    #pragma unroll
    for (int i = 0; i < 4; ++i)
        tile[ty + 8 * i][tx] = in[(size_t)(k0 + ty + 8 * i) * N + n0 + tx];
    __syncthreads();
    #pragma unroll
    for (int i = 0; i < 4; ++i)
        outb[(size_t)(n0 + ty + 8 * i) * ostride + k0 + tx] = (short)f2bf(tile[tx][ty + 8 * i]);
}

// ---------------- gathers (bf16 in/out, fp32 accumulate) ----------------
__global__ __launch_bounds__(256) void gather_add_d128(
    const short* __restrict__ feat,    // M x 128 (unpadded)
    const int* __restrict__ rowptr, const int* __restrict__ srcs,
    short* __restrict__ outb, int M)   // M x S1
{
    const int row = blockIdx.x * 4 + (threadIdx.x >> 6);
    if (row >= M) return;
    const int o = (threadIdx.x & 63) * 2;
    unsigned int u = *(const unsigned int*)(feat + (size_t)row * 128 + o);
    float a0 = bf2f(u & 0xffff), a1 = bf2f(u >> 16);
    const int jb = rowptr[row], je = rowptr[row + 1];
    int s_next = (jb < je) ? srcs[jb] : 0;
    for (int j = jb; j < je; ++j) {
        const int s = s_next;
        if (j + 1 < je) s_next = srcs[j + 1];
        const unsigned int v = *(const unsigned int*)(feat + (size_t)s * 128 + o);
        a0 += bf2f(v & 0xffff);
        a1 += bf2f(v >> 16);
    }
    const unsigned int up = (unsigned int)f2bf(a0) | ((unsigned int)f2bf(a1) << 16);
    *(unsigned int*)(outb + (size_t)row * S1 + o) = up;
}

__global__ __launch_bounds__(256) void gather_add_d256(
    const short* __restrict__ feat,    // M x 256 (unpadded)
    const int* __restrict__ rowptr, const int* __restrict__ srcs,
    short* __restrict__ outb, int M)   // M x S2
{
    const int row = blockIdx.x * 4 + (threadIdx.x >> 6);
    if (row >= M) return;
    const int o = (threadIdx.x & 63) * 4;
    uint2 u = *(const uint2*)(feat + (size_t)row * 256 + o);
    float a0 = bf2f(u.x & 0xffff), a1 = bf2f(u.x >> 16);
    float a2 = bf2f(u.y & 0xffff), a3 = bf2f(u.y >> 16);
    const int jb = rowptr[row], je = rowptr[row + 1];
    int s_next = (jb < je) ? srcs[jb] : 0;
    for (int j = jb; j < je; ++j) {
        const int s = s_next;
        if (j + 1 < je) s_next = srcs[j + 1];
        const uint2 v = *(const uint2*)(feat + (size_t)s * 256 + o);
        a0 += bf2f(v.x & 0xffff);
        a1 += bf2f(v.x >> 16);
        a2 += bf2f(v.y & 0xffff);
        a3 += bf2f(v.y >> 16);
    }
    uint2 up;
    up.x = (unsigned int)f2bf(a0) | ((unsigned int)f2bf(a1) << 16);
    up.y = (unsigned int)f2bf(a2) | ((unsigned int)f2bf(a3) << 16);
    *(uint2*)(outb + (size_t)row * S2 + o) = up;
}

// ---------------- layer1: h1 = relu(relu(h1in@w1+b1)@w2+b2) ----------------
// Block: 64 rows x 256 cols, 4 waves (64-col stripe each). A/B frags direct
// from global (padded rows). t1 lives only in LDS.
__global__ __launch_bounds__(256) void layer1_fused(
    const short* __restrict__ h1in,   // M x S1 (payload 128)
    const short* __restrict__ w1t,    // 256 x S1 (payload 128)
    const float* __restrict__ b1,
    const short* __restrict__ w2t,    // 256 x S2 (payload 256)
    const float* __restrict__ b2,
    short* __restrict__ h1,           // M x 256 (unpadded)
    int M)
{
    __shared__ short sT[64 * S2];
    const int tid  = threadIdx.x;
    const int lane = tid & 63;
    const int wid  = tid >> 6;
    const int r16  = lane & 15;
    const int q    = lane >> 4;
    const int tm   = blockIdx.x * 64;
    const int wn   = wid * 64;

    f32x4 acc[4][4];
    #pragma unroll
    for (int i = 0; i < 4; ++i)
        #pragma unroll
        for (int j = 0; j < 4; ++j)
            acc[i][j] = (f32x4)0.f;

    // ---- GEMM1: t1 = relu(h1in @ w1 + b1), K = 128 ----
    const short* Abase = h1in + (size_t)tm * S1;
    #pragma unroll
    for (int k0 = 0; k0 < 128; k0 += 32) {
        bf16x8 af[4], bfr[4];
        #pragma unroll
        for (int i = 0; i < 4; ++i)
            af[i] = *(const bf16x8*)(Abase + (size_t)(i * 16 + r16) * S1 + k0 + q * 8);
        #pragma unroll
        for (int j = 0; j < 4; ++j)
            bfr[j] = *(const bf16x8*)(w1t + (size_t)(wn + j * 16 + r16) * S1 + k0 + q * 8);
        #pragma unroll
        for (int i = 0; i < 4; ++i)
            #pragma unroll
            for (int j = 0; j < 4; ++j)
                acc[i][j] = __builtin_amdgcn_mfma_f32_16x16x32_bf16(af[i], bfr[j], acc[i][j], 0, 0, 0);
    }

    // epilogue1 -> sT  (row = i*16 + q*4 + r, col = wn + j*16 + r16)
    #pragma unroll
    for (int j = 0; j < 4; ++j) {
        const int col = wn + j * 16 + r16;
        const float bj = b1[col];
        #pragma unroll
        for (int i = 0; i < 4; ++i)
            #pragma unroll
            for (int r = 0; r < 4; ++r) {
                float v = fmaxf(acc[i][j][r] + bj, 0.f);
                sT[(i * 16 + q * 4 + r) * S2 + col] = (short)f2bf(v);
            }
    }
    __syncthreads();

    // ---- GEMM2: h1 = relu(t1 @ w2 + b2), K = 256, A from LDS ----
    #pragma unroll
    for (int i = 0; i < 4; ++i)
        #pragma unroll
        for (int j = 0; j < 4; ++j)
            acc[i][j] = (f32x4)0.f;

    #pragma unroll
    for (int k0 = 0; k0 < 256; k0 += 32) {
        bf16x8 af[4], bfr[4];
        #pragma unroll
        for (int i = 0; i < 4; ++i)
            af[i] = *(const bf16x8*)(&sT[(i * 16 + r16) * S2 + k0 + q * 8]);
        #pragma unroll
        for (int j = 0; j < 4; ++j)
            bfr[j] = *(const bf16x8*)(w2t + (size_t)(wn + j * 16 + r16) * S2 + k0 + q * 8);
        #pragma unroll
        for (int i = 0; i < 4; ++i)
            #pragma unroll
            for (int j = 0; j < 4; ++j)
                acc[i][j] = __builtin_amdgcn_mfma_f32_16x16x32_bf16(af[i], bfr[j], acc[i][j], 0, 0, 0);
    }
    __syncthreads();   // all waves done reading sT

    // epilogue2 -> sT (reused as h1 tile), then coalesced store
    #pragma unroll
    for (int j = 0; j < 4; ++j) {
        const int col = wn + j * 16 + r16;
        const float bj = b2[col];
        #pragma unroll
        for (int i = 0; i < 4; ++i)
            #pragma unroll
            for (int r = 0; r < 4; ++r) {
                float v = fmaxf(acc[i][j][r] + bj, 0.f);
                sT[(i * 16 + q * 4 + r) * S2 + col] = (short)f2bf(v);
            }
    }
    __syncthreads();

    // 64 rows x 512B payload; 2048 16B-chunks over 256 threads
    #pragma unroll
    for (int c = 0; c < 8; ++c) {
        const int idx = tid + c * 256;
        const int row = idx >> 5;
        const int ch  = idx & 31;
        const int rg  = tm + row;
        if (rg < M) {
            const uint4 v = *(const uint4*)(&sT[row * S2 + ch * 8]);
            *(uint4*)(h1 + (size_t)rg * 256 + ch * 8) = v;
        }
    }
}

// ---------------- layer2: out = log_softmax(relu(h2in@w3+b3) @ w4 + b4) ----------------
__global__ __launch_bounds__(256) void layer2_fused(
    const short* __restrict__ h2in,   // M x S2 (payload 256)
    const short* __restrict__ w3t,    // 256 x S2
    const float* __restrict__ b3,
    const float* __restrict__ w4,     // 256 x 2 fp32
    const float* __restrict__ b4,
    float* __restrict__ out,          // M x 2
    int M)
{
    __shared__ short sT[64 * S2];
    const int tid  = threadIdx.x;
    const int lane = tid & 63;
    const int wid  = tid >> 6;
    const int r16  = lane & 15;
    const int q    = lane >> 4;
    const int tm   = blockIdx.x * 64;
    const int wn   = wid * 64;

    f32x4 acc[4][4];
    #pragma unroll
    for (int i = 0; i < 4; ++i)
        #pragma unroll
        for (int j = 0; j < 4; ++j)
            acc[i][j] = (f32x4)0.f;

    const short* Abase = h2in + (size_t)tm * S2;
    #pragma unroll
    for (int k0 = 0; k0 < 256; k0 += 32) {
        bf16x8 af[4], bfr[4];
        #pragma unroll
        for (int i = 0; i < 4; ++i)
            af[i] = *(const bf16x8*)(Abase + (size_t)(i * 16 + r16) * S2 + k0 + q * 8);
        #pragma unroll
        for (int j = 0; j < 4; ++j)
            bfr[j] = *(const bf16x8*)(w3t + (size_t)(wn + j * 16 + r16) * S2 + k0 + q * 8);
        #pragma unroll
        for (int i = 0; i < 4; ++i)
            #pragma unroll
            for (int j = 0; j < 4; ++j)
                acc[i][j] = __builtin_amdgcn_mfma_f32_16x16x32_bf16(af[i], bfr[j], acc[i][j], 0, 0, 0);
    }

    // epilogue -> sT (t2 tile, bf16 + relu + bias)
    #pragma unroll
    for (int j = 0; j < 4; ++j) {
        const int col = wn + j * 16 + r16;
        const float bj = b3[col];
        #pragma unroll
        for (int i = 0; i < 4; ++i)
            #pragma unroll
            for (int r = 0; r < 4; ++r) {
                float v = fmaxf(acc[i][j][r] + bj, 0.f);
                sT[(i * 16 + q * 4 + r) * S2 + col] = (short)f2bf(v);
            }
    }
    __syncthreads();

    // head: 4 threads per row, 64 k each; shuffle-reduce width 4
    const int row = tid >> 2;
    const int qd  = tid & 3;
    const short* tp = &sT[row * S2 + qd * 64];
    const float* w4p = w4 + qd * 128;
    float s0 = 0.f, s1 = 0.f;
    #pragma unroll 8
    for (int k = 0; k < 64; ++k) {
        const float a = bf2f((unsigned short)tp[k]);
        const float2 w = *(const float2*)(w4p + 2 * k);
        s0 = fmaf(a, w.x, s0);
        s1 = fmaf(a, w.y, s1);
    }
    s0 += __shfl_down(s0, 2, 4);  s1 += __shfl_down(s1, 2, 4);
    s0 += __shfl_down(s0, 1, 4);  s1 += __shfl_down(s1, 1, 4);
    if (qd == 0) {
        const int rg = tm + row;
        if (rg < M) {
            s0 += b4[0];
            s1 += b4[1];
            const float m = fmaxf(s0, s1);
            const float l = logf(__expf(s0 - m) + __expf(s1 - m));
            float2 o;
            o.x = s0 - m - l;
            o.y = s1 - m - l;
            *(float2*)(out + (size_t)rg * 2) = o;
        }
    }
}

extern "C" void kernel_launch(void* const* d_in, const int* in_sizes, int n_in,
                              void* d_out, int out_size, void* d_ws, size_t ws_size,
                              hipStream_t stream)
{
    const float* x  = (const float*)d_in[0];
    const int*   ei = (const int*)d_in[1];
    const float* w1 = (const float*)d_in[2];
    const float* b1 = (const float*)d_in[3];
    const float* w2 = (const float*)d_in[4];
    const float* b2 = (const float*)d_in[5];
    const float* w3 = (const float*)d_in[6];
    const float* b3 = (const float*)d_in[7];
    const float* w4 = (const float*)d_in[8];
    const float* b4 = (const float*)d_in[9];

    const int DIN = 128, DH = 256;
    const int M = in_sizes[0] / DIN;   // 50000
    const int E = in_sizes[1] / 2;     // 600000
    const int* src = ei;
    const int* dst = ei + E;

    // -------- workspace layout --------
    int* deg    = (int*)d_ws;
    int* cur    = deg + M;
    int* rowptr = cur + M;
    int* srcs   = rowptr + (M + 1);
    size_t off = ((size_t)(3 * M + 1 + E) * sizeof(int) + 255) & ~(size_t)255;
    short* x_bf = (short*)((char*)d_ws + off);  off += (size_t)M * DIN * 2;       // M x 128
    off = (off + 255) & ~(size_t)255;
    short* h1in = (short*)((char*)d_ws + off);  off += (size_t)M * S1 * 2;        // M x 136
    off = (off + 255) & ~(size_t)255;
    short* h1   = (short*)((char*)d_ws + off);  off += (size_t)M * DH * 2;        // M x 256
    off = (off + 255) & ~(size_t)255;
    short* h2in = (short*)((char*)d_ws + off);  off += (size_t)M * S2 * 2;        // M x 264
    off = (off + 255) & ~(size_t)255;
    short* w1t  = (short*)((char*)d_ws + off);  off += (size_t)DH * S1 * 2;       // 256 x 136
    off = (off + 255) & ~(size_t)255;
    short* w2t  = (short*)((char*)d_ws + off);  off += (size_t)DH * S2 * 2;       // 256 x 264
    off = (off + 255) & ~(size_t)255;
    short* w3t  = (short*)((char*)d_ws + off);  off += (size_t)DH * S2 * 2;       // 256 x 264

    // -------- CSR build --------
    hipMemsetAsync(deg, 0, (size_t)M * sizeof(int), stream);
    degree_kernel<<<(E + 255) / 256, 256, 0, stream>>>(dst, deg, E);
    scan_kernel<<<1, SCAN_THREADS, 0, stream>>>(deg, rowptr, cur, M);
    fill_kernel<<<(E + 255) / 256, 256, 0, stream>>>(src, dst, cur, srcs, E);

    // -------- converts --------
    cvt_bf16_kernel<<<((M * DIN / 4) + 255) / 256, 256, 0, stream>>>(x, x_bf, M * DIN / 4);
    transpose_cvt_kernel<<<dim3(DIN / 32, DH / 32), 256, 0, stream>>>(w1, w1t, DIN, DH, S1);
    transpose_cvt_kernel<<<dim3(DH / 32, DH / 32), 256, 0, stream>>>(w2, w2t, DH, DH, S2);
    transpose_cvt_kernel<<<dim3(DH / 32, DH / 32), 256, 0, stream>>>(w3, w3t, DH, DH, S2);

    const int nblk = (M + 63) / 64;

    // -------- layer 1 --------
    gather_add_d128<<<(M + 3) / 4, 256, 0, stream>>>(x_bf, rowptr, srcs, h1in, M);
    layer1_fused<<<nblk, 256, 0, stream>>>(h1in, w1t, b1, w2t, b2, h1, M);

    // -------- layer 2 --------
    gather_add_d256<<<(M + 3) / 4, 256, 0, stream>>>(h1, rowptr, srcs, h2in, M);
    layer2_fused<<<nblk, 256, 0, stream>>>(h2in, w3t, b3, w4, b4, (float*)d_out, M);
}

// Round 4
// 315.564 us; speedup vs baseline: 10.7651x; 1.3117x over previous
//
#include <hip/hip_runtime.h>
#include <hip/hip_bf16.h>

// GIN 2-layer forward — R4: R3 + fast two-level CSR scan (the 110µs
// single-block scan was 27% of runtime at 0.14% occupancy).
//
//   CSR build: degree -> block_sum -> scan_partials -> scan_blocks -> fill
//   x_bf  = bf16(x);  w{1,2,3}t = bf16(w^T) padded
//   h1in  = x_bf + gather(x_bf)                     [bf16, stride 136]
//   h1    = relu(relu(h1in@w1+b1)@w2+b2)            [layer1_fused, t1 in LDS only]
//   h2in  = h1 + gather(h1)                         [bf16, stride 264]
//   out   = log_softmax(relu(h2in@w3+b3)@w4+b4)     [layer2_fused, t2 in LDS only]

typedef __attribute__((ext_vector_type(8))) short bf16x8;
typedef __attribute__((ext_vector_type(4))) float f32x4;

static __device__ __forceinline__ unsigned short f2bf(float f) {
    unsigned int u = __float_as_uint(f);
    unsigned int r = (u + 0x7fffu + ((u >> 16) & 1u)) >> 16;
    return (unsigned short)r;
}
static __device__ __forceinline__ float bf2f(unsigned short s) {
    return __uint_as_float(((unsigned int)s) << 16);
}

#define S1 136   // 128 + 8 pad (bf16 elems)
#define S2 264   // 256 + 8 pad

// ---------------- CSR build ----------------
__global__ __launch_bounds__(256) void degree_kernel(
    const int* __restrict__ dst, int* __restrict__ deg, int E)
{
    const int e = blockIdx.x * 256 + threadIdx.x;
    if (e < E) atomicAdd(&deg[dst[e]], 1);
}

// 1024 elems per block -> bsum[b]
__global__ __launch_bounds__(256) void block_sum_kernel(
    const int* __restrict__ deg, int* __restrict__ bsum, int M)
{
    const int b = blockIdx.x, t = threadIdx.x;
    const int idx = b * 1024 + t * 4;
    int s = 0;
    if (idx + 3 < M) {
        const int4 v = *(const int4*)(deg + idx);
        s = v.x + v.y + v.z + v.w;
    } else {
        #pragma unroll
        for (int i = 0; i < 4; ++i) if (idx + i < M) s += deg[idx + i];
    }
    #pragma unroll
    for (int off = 32; off > 0; off >>= 1) s += __shfl_down(s, off);
    __shared__ int ws[4];
    if ((t & 63) == 0) ws[t >> 6] = s;
    __syncthreads();
    if (t == 0) bsum[b] = ws[0] + ws[1] + ws[2] + ws[3];
}

// exclusive scan of up to 64 block sums (one wave)
__global__ __launch_bounds__(64) void scan_partials_kernel(
    const int* __restrict__ bsum, int* __restrict__ boff, int nB)
{
    const int t = threadIdx.x;
    const int v = (t < nB) ? bsum[t] : 0;
    int inc = v;
    #pragma unroll
    for (int off = 1; off < 64; off <<= 1) {
        const int u = __shfl_up(inc, off);
        if (t >= off) inc += u;
    }
    if (t < nB) boff[t] = inc - v;
}

// full exclusive scan: rowptr/cur for 1024 elems per block, offset by boff[b]
__global__ __launch_bounds__(256) void scan_blocks_kernel(
    const int* __restrict__ deg, const int* __restrict__ boff,
    int* __restrict__ rowptr, int* __restrict__ cur, int M, int E)
{
    const int b = blockIdx.x, t = threadIdx.x;
    const int idx = b * 1024 + t * 4;
    int4 d = make_int4(0, 0, 0, 0);
    if (idx + 3 < M) {
        d = *(const int4*)(deg + idx);
    } else {
        if (idx + 0 < M) d.x = deg[idx + 0];
        if (idx + 1 < M) d.y = deg[idx + 1];
        if (idx + 2 < M) d.z = deg[idx + 2];
        if (idx + 3 < M) d.w = deg[idx + 3];
    }
    const int tot = d.x + d.y + d.z + d.w;
    const int lane = t & 63, wid = t >> 6;
    int inc = tot;
    #pragma unroll
    for (int off = 1; off < 64; off <<= 1) {
        const int u = __shfl_up(inc, off);
        if (lane >= off) inc += u;
    }
    __shared__ int wsum[4];
    if (lane == 63) wsum[wid] = inc;
    __syncthreads();
    int woff = 0;
    #pragma unroll
    for (int w = 0; w < 4; ++w) if (w < wid) woff += wsum[w];
    int p = boff[b] + woff + (inc - tot);   // exclusive prefix for elem idx
    if (idx + 0 < M) { rowptr[idx + 0] = p; cur[idx + 0] = p; } p += d.x;
    if (idx + 1 < M) { rowptr[idx + 1] = p; cur[idx + 1] = p; } p += d.y;
    if (idx + 2 < M) { rowptr[idx + 2] = p; cur[idx + 2] = p; } p += d.z;
    if (idx + 3 < M) { rowptr[idx + 3] = p; cur[idx + 3] = p; }
    if (b == 0 && t == 0) rowptr[M] = E;    // total degree == E by construction
}

__global__ __launch_bounds__(256) void fill_kernel(
    const int* __restrict__ src, const int* __restrict__ dst,
    int* __restrict__ cur, int* __restrict__ srcs, int E)
{
    const int e = blockIdx.x * 256 + threadIdx.x;
    if (e >= E) return;
    const int p = atomicAdd(&cur[dst[e]], 1);
    srcs[p] = src[e];
}

// ---------------- converts ----------------
__global__ __launch_bounds__(256) void cvt_bf16_kernel(
    const float* __restrict__ in, short* __restrict__ outb, int n4)
{
    const int i = (blockIdx.x * 256 + threadIdx.x);
    if (i >= n4) return;
    const float4 v = *(const float4*)(in + (size_t)i * 4);
    ushort4 o;
    o.x = f2bf(v.x); o.y = f2bf(v.y); o.z = f2bf(v.z); o.w = f2bf(v.w);
    *(ushort4*)(outb + (size_t)i * 4) = o;
}

// out[n][k] (bf16, row stride ostride) = in[k][n] (fp32, K x N)
__global__ __launch_bounds__(256) void transpose_cvt_kernel(
    const float* __restrict__ in, short* __restrict__ outb,
    int K, int N, int ostride)
{
    __shared__ float tile[32][33];
    const int k0 = blockIdx.x * 32;
    const int n0 = blockIdx.y * 32;
    const int tx = threadIdx.x & 31;
    const int ty = threadIdx.x >> 5;   // 0..7
    #pragma unroll
    for (int i = 0; i < 4; ++i)
        tile[ty + 8 * i][tx] = in[(size_t)(k0 + ty + 8 * i) * N + n0 + tx];
    __syncthreads();
    #pragma unroll
    for (int i = 0; i < 4; ++i)
        outb[(size_t)(n0 + ty + 8 * i) * ostride + k0 + tx] = (short)f2bf(tile[tx][ty + 8 * i]);
}

// ---------------- gathers (bf16 in/out, fp32 accumulate) ----------------
__global__ __launch_bounds__(256) void gather_add_d128(
    const short* __restrict__ feat,    // M x 128 (unpadded)
    const int* __restrict__ rowptr, const int* __restrict__ srcs,
    short* __restrict__ outb, int M)   // M x S1
{
    const int row = blockIdx.x * 4 + (threadIdx.x >> 6);
    if (row >= M) return;
    const int o = (threadIdx.x & 63) * 2;
    unsigned int u = *(const unsigned int*)(feat + (size_t)row * 128 + o);
    float a0 = bf2f(u & 0xffff), a1 = bf2f(u >> 16);
    const int jb = rowptr[row], je = rowptr[row + 1];
    int s_next = (jb < je) ? srcs[jb] : 0;
    for (int j = jb; j < je; ++j) {
        const int s = s_next;
        if (j + 1 < je) s_next = srcs[j + 1];
        const unsigned int v = *(const unsigned int*)(feat + (size_t)s * 128 + o);
        a0 += bf2f(v & 0xffff);
        a1 += bf2f(v >> 16);
    }
    const unsigned int up = (unsigned int)f2bf(a0) | ((unsigned int)f2bf(a1) << 16);
    *(unsigned int*)(outb + (size_t)row * S1 + o) = up;
}

__global__ __launch_bounds__(256) void gather_add_d256(
    const short* __restrict__ feat,    // M x 256 (unpadded)
    const int* __restrict__ rowptr, const int* __restrict__ srcs,
    short* __restrict__ outb, int M)   // M x S2
{
    const int row = blockIdx.x * 4 + (threadIdx.x >> 6);
    if (row >= M) return;
    const int o = (threadIdx.x & 63) * 4;
    uint2 u = *(const uint2*)(feat + (size_t)row * 256 + o);
    float a0 = bf2f(u.x & 0xffff), a1 = bf2f(u.x >> 16);
    float a2 = bf2f(u.y & 0xffff), a3 = bf2f(u.y >> 16);
    const int jb = rowptr[row], je = rowptr[row + 1];
    int s_next = (jb < je) ? srcs[jb] : 0;
    for (int j = jb; j < je; ++j) {
        const int s = s_next;
        if (j + 1 < je) s_next = srcs[j + 1];
        const uint2 v = *(const uint2*)(feat + (size_t)s * 256 + o);
        a0 += bf2f(v.x & 0xffff);
        a1 += bf2f(v.x >> 16);
        a2 += bf2f(v.y & 0xffff);
        a3 += bf2f(v.y >> 16);
    }
    uint2 up;
    up.x = (unsigned int)f2bf(a0) | ((unsigned int)f2bf(a1) << 16);
    up.y = (unsigned int)f2bf(a2) | ((unsigned int)f2bf(a3) << 16);
    *(uint2*)(outb + (size_t)row * S2 + o) = up;
}

// ---------------- layer1: h1 = relu(relu(h1in@w1+b1)@w2+b2) ----------------
__global__ __launch_bounds__(256) void layer1_fused(
    const short* __restrict__ h1in,   // M x S1 (payload 128)
    const short* __restrict__ w1t,    // 256 x S1 (payload 128)
    const float* __restrict__ b1,
    const short* __restrict__ w2t,    // 256 x S2 (payload 256)
    const float* __restrict__ b2,
    short* __restrict__ h1,           // M x 256 (unpadded)
    int M)
{
    __shared__ short sT[64 * S2];
    const int tid  = threadIdx.x;
    const int lane = tid & 63;
    const int wid  = tid >> 6;
    const int r16  = lane & 15;
    const int q    = lane >> 4;
    const int tm   = blockIdx.x * 64;
    const int wn   = wid * 64;

    f32x4 acc[4][4];
    #pragma unroll
    for (int i = 0; i < 4; ++i)
        #pragma unroll
        for (int j = 0; j < 4; ++j)
            acc[i][j] = (f32x4)0.f;

    // ---- GEMM1: t1 = relu(h1in @ w1 + b1), K = 128 ----
    const short* Abase = h1in + (size_t)tm * S1;
    #pragma unroll
    for (int k0 = 0; k0 < 128; k0 += 32) {
        bf16x8 af[4], bfr[4];
        #pragma unroll
        for (int i = 0; i < 4; ++i)
            af[i] = *(const bf16x8*)(Abase + (size_t)(i * 16 + r16) * S1 + k0 + q * 8);
        #pragma unroll
        for (int j = 0; j < 4; ++j)
            bfr[j] = *(const bf16x8*)(w1t + (size_t)(wn + j * 16 + r16) * S1 + k0 + q * 8);
        #pragma unroll
        for (int i = 0; i < 4; ++i)
            #pragma unroll
            for (int j = 0; j < 4; ++j)
                acc[i][j] = __builtin_amdgcn_mfma_f32_16x16x32_bf16(af[i], bfr[j], acc[i][j], 0, 0, 0);
    }

    // epilogue1 -> sT  (row = i*16 + q*4 + r, col = wn + j*16 + r16)
    #pragma unroll
    for (int j = 0; j < 4; ++j) {
        const int col = wn + j * 16 + r16;
        const float bj = b1[col];
        #pragma unroll
        for (int i = 0; i < 4; ++i)
            #pragma unroll
            for (int r = 0; r < 4; ++r) {
                float v = fmaxf(acc[i][j][r] + bj, 0.f);
                sT[(i * 16 + q * 4 + r) * S2 + col] = (short)f2bf(v);
            }
    }
    __syncthreads();

    // ---- GEMM2: h1 = relu(t1 @ w2 + b2), K = 256, A from LDS ----
    #pragma unroll
    for (int i = 0; i < 4; ++i)
        #pragma unroll
        for (int j = 0; j < 4; ++j)
            acc[i][j] = (f32x4)0.f;

    #pragma unroll
    for (int k0 = 0; k0 < 256; k0 += 32) {
        bf16x8 af[4], bfr[4];
        #pragma unroll
        for (int i = 0; i < 4; ++i)
            af[i] = *(const bf16x8*)(&sT[(i * 16 + r16) * S2 + k0 + q * 8]);
        #pragma unroll
        for (int j = 0; j < 4; ++j)
            bfr[j] = *(const bf16x8*)(w2t + (size_t)(wn + j * 16 + r16) * S2 + k0 + q * 8);
        #pragma unroll
        for (int i = 0; i < 4; ++i)
            #pragma unroll
            for (int j = 0; j < 4; ++j)
                acc[i][j] = __builtin_amdgcn_mfma_f32_16x16x32_bf16(af[i], bfr[j], acc[i][j], 0, 0, 0);
    }
    __syncthreads();   // all waves done reading sT

    // epilogue2 -> sT (reused as h1 tile), then coalesced store
    #pragma unroll
    for (int j = 0; j < 4; ++j) {
        const int col = wn + j * 16 + r16;
        const float bj = b2[col];
        #pragma unroll
        for (int i = 0; i < 4; ++i)
            #pragma unroll
            for (int r = 0; r < 4; ++r) {
                float v = fmaxf(acc[i][j][r] + bj, 0.f);
                sT[(i * 16 + q * 4 + r) * S2 + col] = (short)f2bf(v);
            }
    }
    __syncthreads();

    // 64 rows x 512B payload; 2048 16B-chunks over 256 threads
    #pragma unroll
    for (int c = 0; c < 8; ++c) {
        const int idx = tid + c * 256;
        const int row = idx >> 5;
        const int ch  = idx & 31;
        const int rg  = tm + row;
        if (rg < M) {
            const uint4 v = *(const uint4*)(&sT[row * S2 + ch * 8]);
            *(uint4*)(h1 + (size_t)rg * 256 + ch * 8) = v;
        }
    }
}

// ---------------- layer2: out = log_softmax(relu(h2in@w3+b3) @ w4 + b4) ----------------
__global__ __launch_bounds__(256) void layer2_fused(
    const short* __restrict__ h2in,   // M x S2 (payload 256)
    const short* __restrict__ w3t,    // 256 x S2
    const float* __restrict__ b3,
    const float* __restrict__ w4,     // 256 x 2 fp32
    const float* __restrict__ b4,
    float* __restrict__ out,          // M x 2
    int M)
{
    __shared__ short sT[64 * S2];
    const int tid  = threadIdx.x;
    const int lane = tid & 63;
    const int wid  = tid >> 6;
    const int r16  = lane & 15;
    const int q    = lane >> 4;
    const int tm   = blockIdx.x * 64;
    const int wn   = wid * 64;

    f32x4 acc[4][4];
    #pragma unroll
    for (int i = 0; i < 4; ++i)
        #pragma unroll
        for (int j = 0; j < 4; ++j)
            acc[i][j] = (f32x4)0.f;

    const short* Abase = h2in + (size_t)tm * S2;
    #pragma unroll
    for (int k0 = 0; k0 < 256; k0 += 32) {
        bf16x8 af[4], bfr[4];
        #pragma unroll
        for (int i = 0; i < 4; ++i)
            af[i] = *(const bf16x8*)(Abase + (size_t)(i * 16 + r16) * S2 + k0 + q * 8);
        #pragma unroll
        for (int j = 0; j < 4; ++j)
            bfr[j] = *(const bf16x8*)(w3t + (size_t)(wn + j * 16 + r16) * S2 + k0 + q * 8);
        #pragma unroll
        for (int i = 0; i < 4; ++i)
            #pragma unroll
            for (int j = 0; j < 4; ++j)
                acc[i][j] = __builtin_amdgcn_mfma_f32_16x16x32_bf16(af[i], bfr[j], acc[i][j], 0, 0, 0);
    }

    // epilogue -> sT (t2 tile, bf16 + relu + bias)
    #pragma unroll
    for (int j = 0; j < 4; ++j) {
        const int col = wn + j * 16 + r16;
        const float bj = b3[col];
        #pragma unroll
        for (int i = 0; i < 4; ++i)
            #pragma unroll
            for (int r = 0; r < 4; ++r) {
                float v = fmaxf(acc[i][j][r] + bj, 0.f);
                sT[(i * 16 + q * 4 + r) * S2 + col] = (short)f2bf(v);
            }
    }
    __syncthreads();

    // head: 4 threads per row, 64 k each; shuffle-reduce width 4
    const int row = tid >> 2;
    const int qd  = tid & 3;
    const short* tp = &sT[row * S2 + qd * 64];
    const float* w4p = w4 + qd * 128;
    float s0 = 0.f, s1 = 0.f;
    #pragma unroll 8
    for (int k = 0; k < 64; ++k) {
        const float a = bf2f((unsigned short)tp[k]);
        const float2 w = *(const float2*)(w4p + 2 * k);
        s0 = fmaf(a, w.x, s0);
        s1 = fmaf(a, w.y, s1);
    }
    s0 += __shfl_down(s0, 2, 4);  s1 += __shfl_down(s1, 2, 4);
    s0 += __shfl_down(s0, 1, 4);  s1 += __shfl_down(s1, 1, 4);
    if (qd == 0) {
        const int rg = tm + row;
        if (rg < M) {
            s0 += b4[0];
            s1 += b4[1];
            const float m = fmaxf(s0, s1);
            const float l = logf(__expf(s0 - m) + __expf(s1 - m));
            float2 o;
            o.x = s0 - m - l;
            o.y = s1 - m - l;
            *(float2*)(out + (size_t)rg * 2) = o;
        }
    }
}

extern "C" void kernel_launch(void* const* d_in, const int* in_sizes, int n_in,
                              void* d_out, int out_size, void* d_ws, size_t ws_size,
                              hipStream_t stream)
{
    const float* x  = (const float*)d_in[0];
    const int*   ei = (const int*)d_in[1];
    const float* w1 = (const float*)d_in[2];
    const float* b1 = (const float*)d_in[3];
    const float* w2 = (const float*)d_in[4];
    const float* b2 = (const float*)d_in[5];
    const float* w3 = (const float*)d_in[6];
    const float* b3 = (const float*)d_in[7];
    const float* w4 = (const float*)d_in[8];
    const float* b4 = (const float*)d_in[9];

    const int DIN = 128, DH = 256;
    const int M = in_sizes[0] / DIN;   // 50000
    const int E = in_sizes[1] / 2;     // 600000
    const int* src = ei;
    const int* dst = ei + E;
    const int nB = (M + 1023) / 1024;  // 49 (<= 64 required by scan_partials)

    // -------- workspace layout --------
    int* deg    = (int*)d_ws;
    int* cur    = deg + M;
    int* rowptr = cur + M;
    int* bsum   = rowptr + (M + 1);
    int* boff   = bsum + 64;
    int* srcs   = boff + 64;
    size_t off = ((size_t)(3 * M + 1 + 128 + E) * sizeof(int) + 255) & ~(size_t)255;
    short* x_bf = (short*)((char*)d_ws + off);  off += (size_t)M * DIN * 2;       // M x 128
    off = (off + 255) & ~(size_t)255;
    short* h1in = (short*)((char*)d_ws + off);  off += (size_t)M * S1 * 2;        // M x 136
    off = (off + 255) & ~(size_t)255;
    short* h1   = (short*)((char*)d_ws + off);  off += (size_t)M * DH * 2;        // M x 256
    off = (off + 255) & ~(size_t)255;
    short* h2in = (short*)((char*)d_ws + off);  off += (size_t)M * S2 * 2;        // M x 264
    off = (off + 255) & ~(size_t)255;
    short* w1t  = (short*)((char*)d_ws + off);  off += (size_t)DH * S1 * 2;       // 256 x 136
    off = (off + 255) & ~(size_t)255;
    short* w2t  = (short*)((char*)d_ws + off);  off += (size_t)DH * S2 * 2;       // 256 x 264
    off = (off + 255) & ~(size_t)255;
    short* w3t  = (short*)((char*)d_ws + off);  off += (size_t)DH * S2 * 2;       // 256 x 264

    // -------- CSR build --------
    hipMemsetAsync(deg, 0, (size_t)M * sizeof(int), stream);
    degree_kernel<<<(E + 255) / 256, 256, 0, stream>>>(dst, deg, E);
    block_sum_kernel<<<nB, 256, 0, stream>>>(deg, bsum, M);
    scan_partials_kernel<<<1, 64, 0, stream>>>(bsum, boff, nB);
    scan_blocks_kernel<<<nB, 256, 0, stream>>>(deg, boff, rowptr, cur, M, E);
    fill_kernel<<<(E + 255) / 256, 256, 0, stream>>>(src, dst, cur, srcs, E);

    // -------- converts --------
    cvt_bf16_kernel<<<((M * DIN / 4) + 255) / 256, 256, 0, stream>>>(x, x_bf, M * DIN / 4);
    transpose_cvt_kernel<<<dim3(DIN / 32, DH / 32), 256, 0, stream>>>(w1, w1t, DIN, DH, S1);
    transpose_cvt_kernel<<<dim3(DH / 32, DH / 32), 256, 0, stream>>>(w2, w2t, DH, DH, S2);
    transpose_cvt_kernel<<<dim3(DH / 32, DH / 32), 256, 0, stream>>>(w3, w3t, DH, DH, S2);

    const int nblk = (M + 63) / 64;

    // -------- layer 1 --------
    gather_add_d128<<<(M + 3) / 4, 256, 0, stream>>>(x_bf, rowptr, srcs, h1in, M);
    layer1_fused<<<nblk, 256, 0, stream>>>(h1in, w1t, b1, w2t, b2, h1, M);

    // -------- layer 2 --------
    gather_add_d256<<<(M + 3) / 4, 256, 0, stream>>>(h1, rowptr, srcs, h2in, M);
    layer2_fused<<<nblk, 256, 0, stream>>>(h2in, w3t, b3, w4, b4, (float*)d_out, M);
}

// Round 5
// 296.407 us; speedup vs baseline: 11.4609x; 1.0646x over previous
//
#include <hip/hip_runtime.h>
#include <hip/hip_bf16.h>

// GIN 2-layer forward — R5: R4 + 4x-unrolled gathers (MLP was 1 row-load
// in flight per wave; gathers were latency-bound at 53/27 µs).
//
//   CSR build: degree -> block_sum -> scan_partials -> scan_blocks -> fill
//   x_bf  = bf16(x);  w{1,2,3}t = bf16(w^T) padded
//   h1in  = x_bf + gather(x_bf)                     [bf16, stride 136]
//   h1    = relu(relu(h1in@w1+b1)@w2+b2)            [layer1_fused, t1 in LDS only]
//   h2in  = h1 + gather(h1)                         [bf16, stride 264]
//   out   = log_softmax(relu(h2in@w3+b3)@w4+b4)     [layer2_fused, t2 in LDS only]

typedef __attribute__((ext_vector_type(8))) short bf16x8;
typedef __attribute__((ext_vector_type(4))) float f32x4;

static __device__ __forceinline__ unsigned short f2bf(float f) {
    unsigned int u = __float_as_uint(f);
    unsigned int r = (u + 0x7fffu + ((u >> 16) & 1u)) >> 16;
    return (unsigned short)r;
}
static __device__ __forceinline__ float bf2f(unsigned short s) {
    return __uint_as_float(((unsigned int)s) << 16);
}
// low/high bf16 of a packed u32 -> f32 (1 VALU op each)
static __device__ __forceinline__ float bflo(unsigned int u) {
    return __uint_as_float(u << 16);
}
static __device__ __forceinline__ float bfhi(unsigned int u) {
    return __uint_as_float(u & 0xffff0000u);
}

#define S1 136   // 128 + 8 pad (bf16 elems)
#define S2 264   // 256 + 8 pad

// ---------------- CSR build ----------------
__global__ __launch_bounds__(256) void degree_kernel(
    const int* __restrict__ dst, int* __restrict__ deg, int E)
{
    const int e = blockIdx.x * 256 + threadIdx.x;
    if (e < E) atomicAdd(&deg[dst[e]], 1);
}

// 1024 elems per block -> bsum[b]
__global__ __launch_bounds__(256) void block_sum_kernel(
    const int* __restrict__ deg, int* __restrict__ bsum, int M)
{
    const int b = blockIdx.x, t = threadIdx.x;
    const int idx = b * 1024 + t * 4;
    int s = 0;
    if (idx + 3 < M) {
        const int4 v = *(const int4*)(deg + idx);
        s = v.x + v.y + v.z + v.w;
    } else {
        #pragma unroll
        for (int i = 0; i < 4; ++i) if (idx + i < M) s += deg[idx + i];
    }
    #pragma unroll
    for (int off = 32; off > 0; off >>= 1) s += __shfl_down(s, off);
    __shared__ int ws[4];
    if ((t & 63) == 0) ws[t >> 6] = s;
    __syncthreads();
    if (t == 0) bsum[b] = ws[0] + ws[1] + ws[2] + ws[3];
}

// exclusive scan of up to 64 block sums (one wave)
__global__ __launch_bounds__(64) void scan_partials_kernel(
    const int* __restrict__ bsum, int* __restrict__ boff, int nB)
{
    const int t = threadIdx.x;
    const int v = (t < nB) ? bsum[t] : 0;
    int inc = v;
    #pragma unroll
    for (int off = 1; off < 64; off <<= 1) {
        const int u = __shfl_up(inc, off);
        if (t >= off) inc += u;
    }
    if (t < nB) boff[t] = inc - v;
}

// full exclusive scan: rowptr/cur for 1024 elems per block, offset by boff[b]
__global__ __launch_bounds__(256) void scan_blocks_kernel(
    const int* __restrict__ deg, const int* __restrict__ boff,
    int* __restrict__ rowptr, int* __restrict__ cur, int M, int E)
{
    const int b = blockIdx.x, t = threadIdx.x;
    const int idx = b * 1024 + t * 4;
    int4 d = make_int4(0, 0, 0, 0);
    if (idx + 3 < M) {
        d = *(const int4*)(deg + idx);
    } else {
        if (idx + 0 < M) d.x = deg[idx + 0];
        if (idx + 1 < M) d.y = deg[idx + 1];
        if (idx + 2 < M) d.z = deg[idx + 2];
        if (idx + 3 < M) d.w = deg[idx + 3];
    }
    const int tot = d.x + d.y + d.z + d.w;
    const int lane = t & 63, wid = t >> 6;
    int inc = tot;
    #pragma unroll
    for (int off = 1; off < 64; off <<= 1) {
        const int u = __shfl_up(inc, off);
        if (lane >= off) inc += u;
    }
    __shared__ int wsum[4];
    if (lane == 63) wsum[wid] = inc;
    __syncthreads();
    int woff = 0;
    #pragma unroll
    for (int w = 0; w < 4; ++w) if (w < wid) woff += wsum[w];
    int p = boff[b] + woff + (inc - tot);   // exclusive prefix for elem idx
    if (idx + 0 < M) { rowptr[idx + 0] = p; cur[idx + 0] = p; } p += d.x;
    if (idx + 1 < M) { rowptr[idx + 1] = p; cur[idx + 1] = p; } p += d.y;
    if (idx + 2 < M) { rowptr[idx + 2] = p; cur[idx + 2] = p; } p += d.z;
    if (idx + 3 < M) { rowptr[idx + 3] = p; cur[idx + 3] = p; }
    if (b == 0 && t == 0) rowptr[M] = E;    // total degree == E by construction
}

__global__ __launch_bounds__(256) void fill_kernel(
    const int* __restrict__ src, const int* __restrict__ dst,
    int* __restrict__ cur, int* __restrict__ srcs, int E)
{
    const int e = blockIdx.x * 256 + threadIdx.x;
    if (e >= E) return;
    const int p = atomicAdd(&cur[dst[e]], 1);
    srcs[p] = src[e];
}

// ---------------- converts ----------------
__global__ __launch_bounds__(256) void cvt_bf16_kernel(
    const float* __restrict__ in, short* __restrict__ outb, int n4)
{
    const int i = (blockIdx.x * 256 + threadIdx.x);
    if (i >= n4) return;
    const float4 v = *(const float4*)(in + (size_t)i * 4);
    ushort4 o;
    o.x = f2bf(v.x); o.y = f2bf(v.y); o.z = f2bf(v.z); o.w = f2bf(v.w);
    *(ushort4*)(outb + (size_t)i * 4) = o;
}

// out[n][k] (bf16, row stride ostride) = in[k][n] (fp32, K x N)
__global__ __launch_bounds__(256) void transpose_cvt_kernel(
    const float* __restrict__ in, short* __restrict__ outb,
    int K, int N, int ostride)
{
    __shared__ float tile[32][33];
    const int k0 = blockIdx.x * 32;
    const int n0 = blockIdx.y * 32;
    const int tx = threadIdx.x & 31;
    const int ty = threadIdx.x >> 5;   // 0..7
    #pragma unroll
    for (int i = 0; i < 4; ++i)
        tile[ty + 8 * i][tx] = in[(size_t)(k0 + ty + 8 * i) * N + n0 + tx];
    __syncthreads();
    #pragma unroll
    for (int i = 0; i < 4; ++i)
        outb[(size_t)(n0 + ty + 8 * i) * ostride + k0 + tx] = (short)f2bf(tile[tx][ty + 8 * i]);
}

// ---------------- gathers (bf16 in/out, fp32 accumulate, 4x unrolled) ----------------
__global__ __launch_bounds__(256) void gather_add_d128(
    const short* __restrict__ feat,    // M x 128 (unpadded)
    const int* __restrict__ rowptr, const int* __restrict__ srcs,
    short* __restrict__ outb, int M)   // M x S1
{
    const int row = blockIdx.x * 4 + (threadIdx.x >> 6);
    if (row >= M) return;
    const int o = (threadIdx.x & 63) * 2;
    const unsigned int u = *(const unsigned int*)(feat + (size_t)row * 128 + o);
    float a0 = bflo(u), a1 = bfhi(u);
    const int jb = rowptr[row], je = rowptr[row + 1];
    int j = jb;
    for (; j + 4 <= je; j += 4) {
        const int s0 = srcs[j + 0];
        const int s1 = srcs[j + 1];
        const int s2 = srcs[j + 2];
        const int s3 = srcs[j + 3];
        const unsigned int v0 = *(const unsigned int*)(feat + (size_t)s0 * 128 + o);
        const unsigned int v1 = *(const unsigned int*)(feat + (size_t)s1 * 128 + o);
        const unsigned int v2 = *(const unsigned int*)(feat + (size_t)s2 * 128 + o);
        const unsigned int v3 = *(const unsigned int*)(feat + (size_t)s3 * 128 + o);
        a0 += bflo(v0); a1 += bfhi(v0);
        a0 += bflo(v1); a1 += bfhi(v1);
        a0 += bflo(v2); a1 += bfhi(v2);
        a0 += bflo(v3); a1 += bfhi(v3);
    }
    for (; j < je; ++j) {
        const int s = srcs[j];
        const unsigned int v = *(const unsigned int*)(feat + (size_t)s * 128 + o);
        a0 += bflo(v); a1 += bfhi(v);
    }
    const unsigned int up = (unsigned int)f2bf(a0) | ((unsigned int)f2bf(a1) << 16);
    *(unsigned int*)(outb + (size_t)row * S1 + o) = up;
}

__global__ __launch_bounds__(256) void gather_add_d256(
    const short* __restrict__ feat,    // M x 256 (unpadded)
    const int* __restrict__ rowptr, const int* __restrict__ srcs,
    short* __restrict__ outb, int M)   // M x S2
{
    const int row = blockIdx.x * 4 + (threadIdx.x >> 6);
    if (row >= M) return;
    const int o = (threadIdx.x & 63) * 4;
    const uint2 u = *(const uint2*)(feat + (size_t)row * 256 + o);
    float a0 = bflo(u.x), a1 = bfhi(u.x);
    float a2 = bflo(u.y), a3 = bfhi(u.y);
    const int jb = rowptr[row], je = rowptr[row + 1];
    int j = jb;
    for (; j + 4 <= je; j += 4) {
        const int s0 = srcs[j + 0];
        const int s1 = srcs[j + 1];
        const int s2 = srcs[j + 2];
        const int s3 = srcs[j + 3];
        const uint2 v0 = *(const uint2*)(feat + (size_t)s0 * 256 + o);
        const uint2 v1 = *(const uint2*)(feat + (size_t)s1 * 256 + o);
        const uint2 v2 = *(const uint2*)(feat + (size_t)s2 * 256 + o);
        const uint2 v3 = *(const uint2*)(feat + (size_t)s3 * 256 + o);
        a0 += bflo(v0.x); a1 += bfhi(v0.x); a2 += bflo(v0.y); a3 += bfhi(v0.y);
        a0 += bflo(v1.x); a1 += bfhi(v1.x); a2 += bflo(v1.y); a3 += bfhi(v1.y);
        a0 += bflo(v2.x); a1 += bfhi(v2.x); a2 += bflo(v2.y); a3 += bfhi(v2.y);
        a0 += bflo(v3.x); a1 += bfhi(v3.x); a2 += bflo(v3.y); a3 += bfhi(v3.y);
    }
    for (; j < je; ++j) {
        const int s = srcs[j];
        const uint2 v = *(const uint2*)(feat + (size_t)s * 256 + o);
        a0 += bflo(v.x); a1 += bfhi(v.x); a2 += bflo(v.y); a3 += bfhi(v.y);
    }
    uint2 up;
    up.x = (unsigned int)f2bf(a0) | ((unsigned int)f2bf(a1) << 16);
    up.y = (unsigned int)f2bf(a2) | ((unsigned int)f2bf(a3) << 16);
    *(uint2*)(outb + (size_t)row * S2 + o) = up;
}

// ---------------- layer1: h1 = relu(relu(h1in@w1+b1)@w2+b2) ----------------
__global__ __launch_bounds__(256) void layer1_fused(
    const short* __restrict__ h1in,   // M x S1 (payload 128)
    const short* __restrict__ w1t,    // 256 x S1 (payload 128)
    const float* __restrict__ b1,
    const short* __restrict__ w2t,    // 256 x S2 (payload 256)
    const float* __restrict__ b2,
    short* __restrict__ h1,           // M x 256 (unpadded)
    int M)
{
    __shared__ short sT[64 * S2];
    const int tid  = threadIdx.x;
    const int lane = tid & 63;
    const int wid  = tid >> 6;
    const int r16  = lane & 15;
    const int q    = lane >> 4;
    const int tm   = blockIdx.x * 64;
    const int wn   = wid * 64;

    f32x4 acc[4][4];
    #pragma unroll
    for (int i = 0; i < 4; ++i)
        #pragma unroll
        for (int j = 0; j < 4; ++j)
            acc[i][j] = (f32x4)0.f;

    // ---- GEMM1: t1 = relu(h1in @ w1 + b1), K = 128 ----
    const short* Abase = h1in + (size_t)tm * S1;
    #pragma unroll
    for (int k0 = 0; k0 < 128; k0 += 32) {
        bf16x8 af[4], bfr[4];
        #pragma unroll
        for (int i = 0; i < 4; ++i)
            af[i] = *(const bf16x8*)(Abase + (size_t)(i * 16 + r16) * S1 + k0 + q * 8);
        #pragma unroll
        for (int j = 0; j < 4; ++j)
            bfr[j] = *(const bf16x8*)(w1t + (size_t)(wn + j * 16 + r16) * S1 + k0 + q * 8);
        #pragma unroll
        for (int i = 0; i < 4; ++i)
            #pragma unroll
            for (int j = 0; j < 4; ++j)
                acc[i][j] = __builtin_amdgcn_mfma_f32_16x16x32_bf16(af[i], bfr[j], acc[i][j], 0, 0, 0);
    }

    // epilogue1 -> sT  (row = i*16 + q*4 + r, col = wn + j*16 + r16)
    #pragma unroll
    for (int j = 0; j < 4; ++j) {
        const int col = wn + j * 16 + r16;
        const float bj = b1[col];
        #pragma unroll
        for (int i = 0; i < 4; ++i)
            #pragma unroll
            for (int r = 0; r < 4; ++r) {
                float v = fmaxf(acc[i][j][r] + bj, 0.f);
                sT[(i * 16 + q * 4 + r) * S2 + col] = (short)f2bf(v);
            }
    }
    __syncthreads();

    // ---- GEMM2: h1 = relu(t1 @ w2 + b2), K = 256, A from LDS ----
    #pragma unroll
    for (int i = 0; i < 4; ++i)
        #pragma unroll
        for (int j = 0; j < 4; ++j)
            acc[i][j] = (f32x4)0.f;

    #pragma unroll
    for (int k0 = 0; k0 < 256; k0 += 32) {
        bf16x8 af[4], bfr[4];
        #pragma unroll
        for (int i = 0; i < 4; ++i)
            af[i] = *(const bf16x8*)(&sT[(i * 16 + r16) * S2 + k0 + q * 8]);
        #pragma unroll
        for (int j = 0; j < 4; ++j)
            bfr[j] = *(const bf16x8*)(w2t + (size_t)(wn + j * 16 + r16) * S2 + k0 + q * 8);
        #pragma unroll
        for (int i = 0; i < 4; ++i)
            #pragma unroll
            for (int j = 0; j < 4; ++j)
                acc[i][j] = __builtin_amdgcn_mfma_f32_16x16x32_bf16(af[i], bfr[j], acc[i][j], 0, 0, 0);
    }
    __syncthreads();   // all waves done reading sT

    // epilogue2 -> sT (reused as h1 tile), then coalesced store
    #pragma unroll
    for (int j = 0; j < 4; ++j) {
        const int col = wn + j * 16 + r16;
        const float bj = b2[col];
        #pragma unroll
        for (int i = 0; i < 4; ++i)
            #pragma unroll
            for (int r = 0; r < 4; ++r) {
                float v = fmaxf(acc[i][j][r] + bj, 0.f);
                sT[(i * 16 + q * 4 + r) * S2 + col] = (short)f2bf(v);
            }
    }
    __syncthreads();

    // 64 rows x 512B payload; 2048 16B-chunks over 256 threads
    #pragma unroll
    for (int c = 0; c < 8; ++c) {
        const int idx = tid + c * 256;
        const int row = idx >> 5;
        const int ch  = idx & 31;
        const int rg  = tm + row;
        if (rg < M) {
            const uint4 v = *(const uint4*)(&sT[row * S2 + ch * 8]);
            *(uint4*)(h1 + (size_t)rg * 256 + ch * 8) = v;
        }
    }
}

// ---------------- layer2: out = log_softmax(relu(h2in@w3+b3) @ w4 + b4) ----------------
__global__ __launch_bounds__(256) void layer2_fused(
    const short* __restrict__ h2in,   // M x S2 (payload 256)
    const short* __restrict__ w3t,    // 256 x S2
    const float* __restrict__ b3,
    const float* __restrict__ w4,     // 256 x 2 fp32
    const float* __restrict__ b4,
    float* __restrict__ out,          // M x 2
    int M)
{
    __shared__ short sT[64 * S2];
    const int tid  = threadIdx.x;
    const int lane = tid & 63;
    const int wid  = tid >> 6;
    const int r16  = lane & 15;
    const int q    = lane >> 4;
    const int tm   = blockIdx.x * 64;
    const int wn   = wid * 64;

    f32x4 acc[4][4];
    #pragma unroll
    for (int i = 0; i < 4; ++i)
        #pragma unroll
        for (int j = 0; j < 4; ++j)
            acc[i][j] = (f32x4)0.f;

    const short* Abase = h2in + (size_t)tm * S2;
    #pragma unroll
    for (int k0 = 0; k0 < 256; k0 += 32) {
        bf16x8 af[4], bfr[4];
        #pragma unroll
        for (int i = 0; i < 4; ++i)
            af[i] = *(const bf16x8*)(Abase + (size_t)(i * 16 + r16) * S2 + k0 + q * 8);
        #pragma unroll
        for (int j = 0; j < 4; ++j)
            bfr[j] = *(const bf16x8*)(w3t + (size_t)(wn + j * 16 + r16) * S2 + k0 + q * 8);
        #pragma unroll
        for (int i = 0; i < 4; ++i)
            #pragma unroll
            for (int j = 0; j < 4; ++j)
                acc[i][j] = __builtin_amdgcn_mfma_f32_16x16x32_bf16(af[i], bfr[j], acc[i][j], 0, 0, 0);
    }

    // epilogue -> sT (t2 tile, bf16 + relu + bias)
    #pragma unroll
    for (int j = 0; j < 4; ++j) {
        const int col = wn + j * 16 + r16;
        const float bj = b3[col];
        #pragma unroll
        for (int i = 0; i < 4; ++i)
            #pragma unroll
            for (int r = 0; r < 4; ++r) {
                float v = fmaxf(acc[i][j][r] + bj, 0.f);
                sT[(i * 16 + q * 4 + r) * S2 + col] = (short)f2bf(v);
            }
    }
    __syncthreads();

    // head: 4 threads per row, 64 k each; shuffle-reduce width 4
    const int row = tid >> 2;
    const int qd  = tid & 3;
    const short* tp = &sT[row * S2 + qd * 64];
    const float* w4p = w4 + qd * 128;
    float s0 = 0.f, s1 = 0.f;
    #pragma unroll 8
    for (int k = 0; k < 64; ++k) {
        const float a = bf2f((unsigned short)tp[k]);
        const float2 w = *(const float2*)(w4p + 2 * k);
        s0 = fmaf(a, w.x, s0);
        s1 = fmaf(a, w.y, s1);
    }
    s0 += __shfl_down(s0, 2, 4);  s1 += __shfl_down(s1, 2, 4);
    s0 += __shfl_down(s0, 1, 4);  s1 += __shfl_down(s1, 1, 4);
    if (qd == 0) {
        const int rg = tm + row;
        if (rg < M) {
            s0 += b4[0];
            s1 += b4[1];
            const float m = fmaxf(s0, s1);
            const float l = logf(__expf(s0 - m) + __expf(s1 - m));
            float2 o;
            o.x = s0 - m - l;
            o.y = s1 - m - l;
            *(float2*)(out + (size_t)rg * 2) = o;
        }
    }
}

extern "C" void kernel_launch(void* const* d_in, const int* in_sizes, int n_in,
                              void* d_out, int out_size, void* d_ws, size_t ws_size,
                              hipStream_t stream)
{
    const float* x  = (const float*)d_in[0];
    const int*   ei = (const int*)d_in[1];
    const float* w1 = (const float*)d_in[2];
    const float* b1 = (const float*)d_in[3];
    const float* w2 = (const float*)d_in[4];
    const float* b2 = (const float*)d_in[5];
    const float* w3 = (const float*)d_in[6];
    const float* b3 = (const float*)d_in[7];
    const float* w4 = (const float*)d_in[8];
    const float* b4 = (const float*)d_in[9];

    const int DIN = 128, DH = 256;
    const int M = in_sizes[0] / DIN;   // 50000
    const int E = in_sizes[1] / 2;     // 600000
    const int* src = ei;
    const int* dst = ei + E;
    const int nB = (M + 1023) / 1024;  // 49 (<= 64 required by scan_partials)

    // -------- workspace layout --------
    int* deg    = (int*)d_ws;
    int* cur    = deg + M;
    int* rowptr = cur + M;
    int* bsum   = rowptr + (M + 1);
    int* boff   = bsum + 64;
    int* srcs   = boff + 64;
    size_t off = ((size_t)(3 * M + 1 + 128 + E) * sizeof(int) + 255) & ~(size_t)255;
    short* x_bf = (short*)((char*)d_ws + off);  off += (size_t)M * DIN * 2;       // M x 128
    off = (off + 255) & ~(size_t)255;
    short* h1in = (short*)((char*)d_ws + off);  off += (size_t)M * S1 * 2;        // M x 136
    off = (off + 255) & ~(size_t)255;
    short* h1   = (short*)((char*)d_ws + off);  off += (size_t)M * DH * 2;        // M x 256
    off = (off + 255) & ~(size_t)255;
    short* h2in = (short*)((char*)d_ws + off);  off += (size_t)M * S2 * 2;        // M x 264
    off = (off + 255) & ~(size_t)255;
    short* w1t  = (short*)((char*)d_ws + off);  off += (size_t)DH * S1 * 2;       // 256 x 136
    off = (off + 255) & ~(size_t)255;
    short* w2t  = (short*)((char*)d_ws + off);  off += (size_t)DH * S2 * 2;       // 256 x 264
    off = (off + 255) & ~(size_t)255;
    short* w3t  = (short*)((char*)d_ws + off);  off += (size_t)DH * S2 * 2;       // 256 x 264

    // -------- CSR build --------
    hipMemsetAsync(deg, 0, (size_t)M * sizeof(int), stream);
    degree_kernel<<<(E + 255) / 256, 256, 0, stream>>>(dst, deg, E);
    block_sum_kernel<<<nB, 256, 0, stream>>>(deg, bsum, M);
    scan_partials_kernel<<<1, 64, 0, stream>>>(bsum, boff, nB);
    scan_blocks_kernel<<<nB, 256, 0, stream>>>(deg, boff, rowptr, cur, M, E);
    fill_kernel<<<(E + 255) / 256, 256, 0, stream>>>(src, dst, cur, srcs, E);

    // -------- converts --------
    cvt_bf16_kernel<<<((M * DIN / 4) + 255) / 256, 256, 0, stream>>>(x, x_bf, M * DIN / 4);
    transpose_cvt_kernel<<<dim3(DIN / 32, DH / 32), 256, 0, stream>>>(w1, w1t, DIN, DH, S1);
    transpose_cvt_kernel<<<dim3(DH / 32, DH / 32), 256, 0, stream>>>(w2, w2t, DH, DH, S2);
    transpose_cvt_kernel<<<dim3(DH / 32, DH / 32), 256, 0, stream>>>(w3, w3t, DH, DH, S2);

    const int nblk = (M + 63) / 64;

    // -------- layer 1 --------
    gather_add_d128<<<(M + 3) / 4, 256, 0, stream>>>(x_bf, rowptr, srcs, h1in, M);
    layer1_fused<<<nblk, 256, 0, stream>>>(h1in, w1t, b1, w2t, b2, h1, M);

    // -------- layer 2 --------
    gather_add_d256<<<(M + 3) / 4, 256, 0, stream>>>(h1, rowptr, srcs, h2in, M);
    layer2_fused<<<nblk, 256, 0, stream>>>(h2in, w3t, b3, w4, b4, (float*)d_out, M);
}